// Round 8
// baseline (102.889 us; speedup 1.0000x reference)
//
#include <hip/hip_runtime.h>
#include <hip/hip_bf16.h>

#define B_N 2048
#define D_V 8
#define F_D 256
#define TILE 128
#define BC 32      // staging chunk: 32 B-cols per stage, double-buffered
#define LSTR 264   // 132 dwords == 4 (mod 32). For ds_*_b128, waves are serviced in
                   // 8-lane phases; lane li's 4-dword window starts at bank 4*li+c ->
                   // windows {0,4,...,28} tile all 32 banks: conflict-free.
                   // (557K count at 264 = benign 2-way sub-phase aliasing, free per
                   // m136. 258 (==1) was a real 4-way: 1.67M, R2. 266 (==5): 2.79M, R5.)

// sqrt(2*log2(e)) : zn scaled by this => MFMA acc = 2*log2(e)*dot => exp(2*dot) = exp2(acc)
#define SCALE_F 1.69864364f

#if defined(__has_builtin)
#  if __has_builtin(__builtin_amdgcn_exp2f)
#    define EXP2F(x) __builtin_amdgcn_exp2f(x)
#  else
#    define EXP2F(x) exp2f(x)
#  endif
#else
#  define EXP2F(x) exp2f(x)
#endif

typedef __attribute__((ext_vector_type(8))) short short8;
typedef __attribute__((ext_vector_type(4))) float floatx4;

__device__ inline unsigned short f2bf(float f) {
    __hip_bfloat16 h = __float2bfloat16(f);
    return *reinterpret_cast<unsigned short*>(&h);
}

__device__ inline float wave_reduce_sum(float v) {
    #pragma unroll
    for (int off = 1; off < 64; off <<= 1)
        v += __shfl_xor(v, off, 64);
    return v;
}

__device__ inline float wave_reduce_max(float v) {
    #pragma unroll
    for (int off = 1; off < 64; off <<= 1)
        v = fmaxf(v, __shfl_xor(v, off, 64));
    return v;
}

// ---------------------------------------------------------------------------
// Kernel 1: fused normalize + pos (R1/R7-verified). Block = 256 threads
// (4 waves) handles 4 samples (32 rows). Each wave normalizes its sample's
// 8 rows (writes scaled bf16 zn to global [d][b][f] AND LDS), then waves 0/1
// compute pos for 2 samples each via MFMA from LDS. Zero-inits ns8.
// ---------------------------------------------------------------------------
__global__ __launch_bounds__(256)
void np_kernel(const float* __restrict__ z, unsigned short* __restrict__ zn,
               float* __restrict__ ns8, float* __restrict__ pos) {
    __shared__ __align__(16) unsigned short Zs[32 * LSTR];  // 16.5 KB
    int tid = threadIdx.x;
    int gid = blockIdx.x * 256 + tid;
    if (gid < D_V * B_N) ns8[gid] = 0.0f;

    int w = tid >> 6, lane = tid & 63;
    int b = blockIdx.x * 4 + w;  // this wave's sample
    #pragma unroll
    for (int k = 0; k < 8; k++) {
        const float4 v = ((const float4*)(z + ((size_t)b * 8 + k) * F_D))[lane];
        float ss = v.x * v.x + v.y * v.y + v.z * v.z + v.w * v.w;
        ss = wave_reduce_sum(ss);
        float inv = SCALE_F / fmaxf(sqrtf(ss), 1e-12f);
        ushort4 o;
        o.x = f2bf(v.x * inv);
        o.y = f2bf(v.y * inv);
        o.z = f2bf(v.z * inv);
        o.w = f2bf(v.w * inv);
        ((ushort4*)(zn + (size_t)k * (B_N * F_D) + (size_t)b * F_D))[lane] = o;
        *(ushort4*)(&Zs[(w * 8 + k) * LSTR + lane * 4]) = o;
    }
    __syncthreads();

    // pos: wave 0 -> local samples 0,1 ; wave 1 -> local samples 2,3
    if (w < 2) {
        int q = lane >> 4, li = lane & 15;
        int lr = (w * 2 + (li >> 3)) * 8 + (li & 7);  // local row: sample*8 + view
        short8 a[8];
        #pragma unroll
        for (int kk = 0; kk < 8; kk++)
            a[kk] = *(const short8*)(&Zs[lr * LSTR + kk * 32 + q * 8]);
        floatx4 acc = {0.f, 0.f, 0.f, 0.f};
        #pragma unroll
        for (int kk = 0; kk < 8; kk++)
            acc = __builtin_amdgcn_mfma_f32_16x16x32_bf16(a[kk], a[kk], acc, 0, 0, 0);
        float p0 = 0.f, p1 = 0.f;
        #pragma unroll
        for (int r = 0; r < 4; r++) {
            int row = q * 4 + r, col = li;
            bool same_sample = (row >> 3) == (col >> 3);
            if (same_sample && row != col) {
                float e = EXP2F(acc[r]);   // acc already = 2*log2e*dot
                if (row < 8) p0 += e; else p1 += e;
            }
        }
        p0 = wave_reduce_sum(p0);
        p1 = wave_reduce_sum(p1);
        if (lane == 0) {
            int s0 = blockIdx.x * 4 + w * 2;
            pos[s0] = p0;
            pos[s0 + 1] = p1;
        }
    }
}

// ---------------------------------------------------------------------------
// Kernel 2 (symmetric-halved): per view d, upper-triangle 128x128 tiles of
// S = exp(2 * Z Z^T): row-sums -> ns8[d][i*128+..]; off-diag tiles also
// col-sums -> ns8[d][j*128+..] (mirrored tile).
// Round-8: occupancy push. 256 threads (4 waves, 32 A-rows each, no spill);
// B staged 32 cols/stage into DOUBLE-BUFFERED LDS (2 x 16.5 KB); T14 kept:
// stage s+2 loads issued right after stage s+1's ds_write, one stage of
// MFMA (~500 cyc) covers L2 latency. breg[4]=32 VGPR (was 64), col-sum via
// in-loop holder cacc[2] (was cs[8]) -> total ~128 VGPR; launch_bounds
// (256,4) = 4 blocks/CU = 16 waves/CU (was 3 blocks at ~160 VGPR).
// One barrier per stage (write targets the idle buffer).
// ---------------------------------------------------------------------------
__global__ __launch_bounds__(256, 4)
void neg_kernel(const unsigned short* __restrict__ zn,
                float* __restrict__ ns8) {
    __shared__ __align__(16) unsigned short Bs[2][BC * LSTR];  // 33 KB
    const int bid = blockIdx.x;
    const int d = bid & 7;            // view == XCD (perf heuristic; FETCH 10.4
                                      // vs 38.7 MB measured, R1 vs R2)
    int trem = bid >> 3;              // 0..135 -> (i,j), i<=j
    int i = 0;
    while (trem >= 16 - i) { trem -= 16 - i; ++i; }
    const int j = i + trem;
    const bool diag = (i == j);
    const unsigned short* Z = zn + (size_t)d * (B_N * F_D);
    int tid = threadIdx.x, w = tid >> 6, lane = tid & 63;
    int q = lane >> 4, li = lane & 15;
    int r0 = i * TILE + w * 32;       // this wave's 32 A-rows
    const int jc = j * TILE;

    // A-frags: issued first, 64 VGPR resident whole kernel
    short8 a[2][8];
    #pragma unroll
    for (int s = 0; s < 2; s++)
        #pragma unroll
        for (int kk = 0; kk < 8; kk++)
            a[s][kk] = *(const short8*)(Z + (size_t)(r0 + s * 16 + li) * F_D + kk * 32 + q * 8);

    // B staging: stage = 32 rows x 256 shorts = 1024 16B-chunks, 4 per thread
    short8 breg[4];
    #pragma unroll
    for (int it = 0; it < 4; ++it) {                    // loads for stage 0
        int idx = it * 256 + tid;
        int row = idx >> 5, kc = idx & 31;
        breg[it] = *(const short8*)(Z + (size_t)(jc + row) * F_D + kc * 8);
    }
    #pragma unroll
    for (int it = 0; it < 4; ++it) {                    // write stage 0 (vmcnt wait
        int idx = it * 256 + tid;                       //  = the one exposed latency)
        int row = idx >> 5, kc = idx & 31;
        *(short8*)(&Bs[0][row * LSTR + kc * 8]) = breg[it];
    }
    #pragma unroll
    for (int it = 0; it < 4; ++it) {                    // loads for stage 1
        int idx = it * 256 + tid;
        int row = idx >> 5, kc = idx & 31;
        breg[it] = *(const short8*)(Z + (size_t)(jc + BC + row) * F_D + kc * 8);
    }

    float rs[2][4];
    #pragma unroll
    for (int s = 0; s < 2; s++)
        #pragma unroll
        for (int r = 0; r < 4; r++) rs[s][r] = 0.f;
    float cacc[2] = {0.f, 0.f};

    __syncthreads();

    #pragma unroll
    for (int st = 0; st < 4; ++st) {
        // ---- compute stage st from Bs[st&1] (32 cols = 2 ct-blocks) ----
        #pragma unroll
        for (int ct = 0; ct < 2; ++ct) {
            const unsigned short* bp = &Bs[st & 1][(ct * 16 + li) * LSTR + q * 8];
            floatx4 acc[2];
            acc[0] = (floatx4){0.f, 0.f, 0.f, 0.f};
            acc[1] = (floatx4){0.f, 0.f, 0.f, 0.f};
            #pragma unroll
            for (int kk = 0; kk < 8; kk++) {
                short8 bf = *(const short8*)(bp + kk * 32);
                acc[0] = __builtin_amdgcn_mfma_f32_16x16x32_bf16(a[0][kk], bf, acc[0], 0, 0, 0);
                acc[1] = __builtin_amdgcn_mfma_f32_16x16x32_bf16(a[1][kk], bf, acc[1], 0, 0, 0);
            }
            // C/D layout: col = li, row(within set) = q*4 + r
            int gcol = jc + st * BC + ct * 16 + li;
            float csum = 0.f;
            #pragma unroll
            for (int s = 0; s < 2; s++) {
                #pragma unroll
                for (int r = 0; r < 4; r++) {
                    float e = EXP2F(acc[s][r]);        // exp(2*dot), 1 trans op
                    if (diag) {                        // uniform: 16/136 blocks
                        int grow = r0 + s * 16 + q * 4 + r;
                        if (grow == gcol) e = 0.f;
                    }
                    rs[s][r] += e;
                    csum += e;
                }
            }
            // colsum holder (saves cs[8]): 16-col block g = st*2+ct; lanes
            // with q == (g&3) keep it in cacc[g>>2]
            csum += __shfl_xor(csum, 16, 64);
            csum += __shfl_xor(csum, 32, 64);
            const int g = st * 2 + ct;
            if (q == (g & 3)) cacc[g >> 2] += csum;
        }
        // ---- ds_write stage st+1 into the idle buffer (vmcnt covered) ----
        if (st < 3) {
            #pragma unroll
            for (int it = 0; it < 4; ++it) {
                int idx = it * 256 + tid;
                int row = idx >> 5, kc = idx & 31;
                *(short8*)(&Bs[(st + 1) & 1][row * LSTR + kc * 8]) = breg[it];
            }
        }
        // ---- issue loads for stage st+2 (breg just freed by the ds_write;
        //      one full compute stage covers their latency) ----
        if (st < 2) {
            #pragma unroll
            for (int it = 0; it < 4; ++it) {
                int idx = it * 256 + tid;
                int row = idx >> 5, kc = idx & 31;
                breg[it] = *(const short8*)(Z + (size_t)(jc + (st + 2) * BC + row) * F_D + kc * 8);
            }
        }
        __syncthreads();
    }

    // row sums: reduce across the 16 column-lanes; lanes li<8 each own one
    // (s,r) value and issue one atomic
    #pragma unroll
    for (int off = 1; off < 16; off <<= 1)
        #pragma unroll
        for (int s = 0; s < 2; s++)
            #pragma unroll
            for (int r = 0; r < 4; r++)
                rs[s][r] += __shfl_xor(rs[s][r], off, 64);
    {
        float rv = 0.f;
        #pragma unroll
        for (int s = 0; s < 2; s++)
            #pragma unroll
            for (int r = 0; r < 4; r++)
                if (li == s * 4 + r) rv = rs[s][r];
        if (li < 8)
            atomicAdd(&ns8[d * B_N + r0 + (li >> 2) * 16 + q * 4 + (li & 3)], rv);
    }

    // col sums (mirrored tile coverage): lane (q,li) holds cols q*16+li and
    // 64+q*16+li; each wave atomics its 32-row partial (4 atomics/col total)
    if (!diag) {
        atomicAdd(&ns8[d * B_N + jc + q * 16 + li], cacc[0]);
        atomicAdd(&ns8[d * B_N + jc + 64 + q * 16 + li], cacc[1]);
    }
}

// ---------------------------------------------------------------------------
// Kernel 3: neg[b] = sum_d ns8[d][b] / (B-1); logits = pos/(pos+neg);
// loss = max + log(sum exp(l-max)) - mean(l). Shuffle-based reductions
// (2 syncthreads instead of 24).
// ---------------------------------------------------------------------------
__global__ void final_kernel(const float* __restrict__ pos,
                             const float* __restrict__ ns8,
                             float* __restrict__ out) {
    __shared__ float redm[4], reds[4], redl[4];
    int t = threadIdx.x, w = t >> 6, lane = t & 63;
    float vals[8];
    float lmax = -1e30f;
    #pragma unroll
    for (int i = 0; i < 8; i++) {
        int idx = t * 8 + i;
        float nsum = 0.f;
        #pragma unroll
        for (int d = 0; d < D_V; d++) nsum += ns8[d * B_N + idx];
        float p = pos[idx];
        float l = p / (p + nsum * (1.0f / (float)(B_N - 1)));
        vals[i] = l;
        lmax = fmaxf(lmax, l);
    }
    lmax = wave_reduce_max(lmax);
    if (lane == 0) redm[w] = lmax;
    __syncthreads();
    float m = fmaxf(fmaxf(redm[0], redm[1]), fmaxf(redm[2], redm[3]));
    float se = 0.f, sl = 0.f;
    #pragma unroll
    for (int i = 0; i < 8; i++) { se += expf(vals[i] - m); sl += vals[i]; }
    se = wave_reduce_sum(se);
    sl = wave_reduce_sum(sl);
    if (lane == 0) { reds[w] = se; redl[w] = sl; }
    __syncthreads();
    if (t == 0) {
        float S = reds[0] + reds[1] + reds[2] + reds[3];
        float L = redl[0] + redl[1] + redl[2] + redl[3];
        out[0] = m + logf(S) - L * (1.0f / (float)B_N);
    }
}

extern "C" void kernel_launch(void* const* d_in, const int* in_sizes, int n_in,
                              void* d_out, int out_size, void* d_ws, size_t ws_size,
                              hipStream_t stream) {
    const float* z = (const float*)d_in[0];
    float* out = (float*)d_out;
    unsigned short* zn = (unsigned short*)d_ws;                        // 8 MB bf16 (pre-scaled)
    float* ns8 = (float*)((char*)d_ws + (size_t)D_V * B_N * F_D * 2);  // 64 KB
    float* pos = ns8 + D_V * B_N;                                      // 8 KB

    np_kernel<<<dim3(512), 256, 0, stream>>>(z, zn, ns8, pos);
    neg_kernel<<<dim3(136 * 8), 256, 0, stream>>>(zn, ns8);
    final_kernel<<<1, 256, 0, stream>>>(pos, ns8, out);
}

// Round 9
// 86.796 us; speedup vs baseline: 1.1854x; 1.1854x over previous
//
#include <hip/hip_runtime.h>
#include <hip/hip_bf16.h>

#define B_N 2048
#define D_V 8
#define F_D 256
#define TILE 128
#define BC 64
#define LSTR 264   // 132 dwords == 4 (mod 32). For ds_*_b128, waves are serviced in
                   // 8-lane phases; lane li's 4-dword window starts at bank 4*li+c ->
                   // windows {0,4,...,28} tile all 32 banks: conflict-free.
                   // (557K at 264 = benign 2-way sub-phase aliasing, free per m136.
                   // 258 (==1): real 4-way, 1.67M, R2. 266 (==5): 2.79M, R5.)

// sqrt(2*log2(e)) : zn scaled by this => MFMA acc = 2*log2(e)*dot => exp(2*dot) = exp2(acc)
#define SCALE_F 1.69864364f

#if defined(__has_builtin)
#  if __has_builtin(__builtin_amdgcn_exp2f)
#    define EXP2F(x) __builtin_amdgcn_exp2f(x)
#  else
#    define EXP2F(x) exp2f(x)
#  endif
#else
#  define EXP2F(x) exp2f(x)
#endif

typedef __attribute__((ext_vector_type(8))) short short8;
typedef __attribute__((ext_vector_type(4))) float floatx4;

__device__ inline unsigned short f2bf(float f) {
    __hip_bfloat16 h = __float2bfloat16(f);
    return *reinterpret_cast<unsigned short*>(&h);
}

__device__ inline float wave_reduce_sum(float v) {
    #pragma unroll
    for (int off = 1; off < 64; off <<= 1)
        v += __shfl_xor(v, off, 64);
    return v;
}

__device__ inline float wave_reduce_max(float v) {
    #pragma unroll
    for (int off = 1; off < 64; off <<= 1)
        v = fmaxf(v, __shfl_xor(v, off, 64));
    return v;
}

// ---------------------------------------------------------------------------
// Kernel 1: fused normalize + pos (R1/R7-verified). Block = 256 threads
// (4 waves) handles 4 samples (32 rows). Each wave normalizes its sample's
// 8 rows (writes scaled bf16 zn to global [d][b][f] AND LDS), then waves 0/1
// compute pos for 2 samples each via MFMA from LDS. Zero-inits ns8.
// ---------------------------------------------------------------------------
__global__ __launch_bounds__(256)
void np_kernel(const float* __restrict__ z, unsigned short* __restrict__ zn,
               float* __restrict__ ns8, float* __restrict__ pos) {
    __shared__ __align__(16) unsigned short Zs[32 * LSTR];  // 16.5 KB
    int tid = threadIdx.x;
    int gid = blockIdx.x * 256 + tid;
    if (gid < D_V * B_N) ns8[gid] = 0.0f;

    int w = tid >> 6, lane = tid & 63;
    int b = blockIdx.x * 4 + w;  // this wave's sample
    #pragma unroll
    for (int k = 0; k < 8; k++) {
        const float4 v = ((const float4*)(z + ((size_t)b * 8 + k) * F_D))[lane];
        float ss = v.x * v.x + v.y * v.y + v.z * v.z + v.w * v.w;
        ss = wave_reduce_sum(ss);
        float inv = SCALE_F / fmaxf(sqrtf(ss), 1e-12f);
        ushort4 o;
        o.x = f2bf(v.x * inv);
        o.y = f2bf(v.y * inv);
        o.z = f2bf(v.z * inv);
        o.w = f2bf(v.w * inv);
        ((ushort4*)(zn + (size_t)k * (B_N * F_D) + (size_t)b * F_D))[lane] = o;
        *(ushort4*)(&Zs[(w * 8 + k) * LSTR + lane * 4]) = o;
    }
    __syncthreads();

    // pos: wave 0 -> local samples 0,1 ; wave 1 -> local samples 2,3
    if (w < 2) {
        int q = lane >> 4, li = lane & 15;
        int lr = (w * 2 + (li >> 3)) * 8 + (li & 7);  // local row: sample*8 + view
        short8 a[8];
        #pragma unroll
        for (int kk = 0; kk < 8; kk++)
            a[kk] = *(const short8*)(&Zs[lr * LSTR + kk * 32 + q * 8]);
        floatx4 acc = {0.f, 0.f, 0.f, 0.f};
        #pragma unroll
        for (int kk = 0; kk < 8; kk++)
            acc = __builtin_amdgcn_mfma_f32_16x16x32_bf16(a[kk], a[kk], acc, 0, 0, 0);
        float p0 = 0.f, p1 = 0.f;
        #pragma unroll
        for (int r = 0; r < 4; r++) {
            int row = q * 4 + r, col = li;
            bool same_sample = (row >> 3) == (col >> 3);
            if (same_sample && row != col) {
                float e = EXP2F(acc[r]);   // acc already = 2*log2e*dot
                if (row < 8) p0 += e; else p1 += e;
            }
        }
        p0 = wave_reduce_sum(p0);
        p1 = wave_reduce_sum(p1);
        if (lane == 0) {
            int s0 = blockIdx.x * 4 + w * 2;
            pos[s0] = p0;
            pos[s0 + 1] = p1;
        }
    }
}

// ---------------------------------------------------------------------------
// Kernel 2 (symmetric-halved): per view d, upper-triangle 128x128 tiles of
// S = exp(2 * Z Z^T): row-sums -> ns8[d][i*128+..]; off-diag tiles also
// col-sums -> ns8[d][j*128+..] (mirrored tile).
// Round-9: R7's VERIFIED pipeline (T14 async-stage, 3 barriers, BC=64),
// re-partitioned 4 waves x 32 rows -> 8 WAVES x 16 ROWS (512 threads) so
// per-wave live state shrinks structurally: a[8]=32 + breg[4]=32 + acc=8 +
// rs=4 + cs=8 + addr ~= 105 VGPR. No launch-bounds squeeze (R8's forced
// 128-cap spilled: VGPR=64 + WRITE 50.8 MB measured). 2 blocks/CU x 8 waves
// = 16 waves/CU (R7: 12), spill-free.
// ---------------------------------------------------------------------------
__global__ __launch_bounds__(512)
void neg_kernel(const unsigned short* __restrict__ zn,
                float* __restrict__ ns8) {
    __shared__ __align__(16) unsigned short Bs[BC * LSTR];  // 33 KB
    const int bid = blockIdx.x;
    const int d = bid & 7;            // view == XCD (perf heuristic; FETCH 10.4
                                      // vs 38.7 MB measured, R1 vs R2)
    int trem = bid >> 3;              // 0..135 -> (i,j), i<=j
    int i = 0;
    while (trem >= 16 - i) { trem -= 16 - i; ++i; }
    const int j = i + trem;
    const bool diag = (i == j);
    const unsigned short* Z = zn + (size_t)d * (B_N * F_D);
    int tid = threadIdx.x, w = tid >> 6, lane = tid & 63;
    int q = lane >> 4, li = lane & 15;
    int r0 = i * TILE + w * 16;       // this wave's 16 A-rows
    const int jc = j * TILE;

    // A-frags: 32 VGPR resident whole kernel (16 rows, K=256)
    short8 a[8];
    #pragma unroll
    for (int kk = 0; kk < 8; kk++)
        a[kk] = *(const short8*)(Z + (size_t)(r0 + li) * F_D + kk * 32 + q * 8);

    // B staging: stage = 64 rows x 256 shorts = 2048 16B-chunks, 4 per thread
    short8 breg[4];
    #pragma unroll
    for (int it = 0; it < 4; ++it) {                    // loads for stage 0
        int idx = it * 512 + tid;
        int row = idx >> 5, kc = idx & 31;
        breg[it] = *(const short8*)(Z + (size_t)(jc + row) * F_D + kc * 8);
    }
    #pragma unroll
    for (int it = 0; it < 4; ++it) {                    // write stage 0 (vmcnt wait
        int idx = it * 512 + tid;                       //  = the one exposed latency)
        int row = idx >> 5, kc = idx & 31;
        *(short8*)(&Bs[row * LSTR + kc * 8]) = breg[it];
    }
    #pragma unroll
    for (int it = 0; it < 4; ++it) {                    // loads for stage 1: issue
        int idx = it * 512 + tid;                       //  NOW, arrive during stage-0
        int row = idx >> 5, kc = idx & 31;              //  compute (T14)
        breg[it] = *(const short8*)(Z + (size_t)(jc + BC + row) * F_D + kc * 8);
    }

    float rs[4] = {0.f, 0.f, 0.f, 0.f};
    float cs[8];

    __syncthreads();

    #pragma unroll
    for (int stage = 0; stage < 2; ++stage) {
        // ---- compute this stage from Bs (64 cols = 4 ct-blocks) ----
        #pragma unroll
        for (int ct = 0; ct < 4; ++ct) {
            const unsigned short* bp = &Bs[(ct * 16 + li) * LSTR + q * 8];
            floatx4 acc = {0.f, 0.f, 0.f, 0.f};
            #pragma unroll
            for (int kk = 0; kk < 8; kk++) {
                short8 bf = *(const short8*)(bp + kk * 32);
                acc = __builtin_amdgcn_mfma_f32_16x16x32_bf16(a[kk], bf, acc, 0, 0, 0);
            }
            // C/D layout: col = li, row(within 16-set) = q*4 + r
            int gcol = jc + stage * BC + ct * 16 + li;
            float csum = 0.f;
            #pragma unroll
            for (int r = 0; r < 4; r++) {
                float e = EXP2F(acc[r]);               // exp(2*dot), 1 trans op
                if (diag) {                            // uniform: 16/136 blocks
                    int grow = r0 + q * 4 + r;
                    if (grow == gcol) e = 0.f;
                }
                rs[r] += e;
                csum += e;
            }
            // col partial over this wave's 16 rows: reduce across q-groups
            csum += __shfl_xor(csum, 16, 64);
            csum += __shfl_xor(csum, 32, 64);
            cs[stage * 4 + ct] = csum;                 // static index
        }
        // ---- stage-1 ds_write into Bs after stage-0 compute (T14) ----
        if (stage == 0) {
            __syncthreads();                           // all reads of Bs done
            #pragma unroll
            for (int it = 0; it < 4; ++it) {
                int idx = it * 512 + tid;
                int row = idx >> 5, kc = idx & 31;
                *(short8*)(&Bs[row * LSTR + kc * 8]) = breg[it];
            }
            __syncthreads();                           // Bs ready
        }
    }

    // row sums: reduce across the 16 column-lanes; lanes li<4 own row q*4+li
    #pragma unroll
    for (int off = 1; off < 16; off <<= 1)
        #pragma unroll
        for (int r = 0; r < 4; r++)
            rs[r] += __shfl_xor(rs[r], off, 64);
    {
        float rv = 0.f;
        #pragma unroll
        for (int r = 0; r < 4; r++)
            if (li == r) rv = rs[r];
        if (li < 4)
            atomicAdd(&ns8[d * B_N + r0 + q * 4 + li], rv);
    }

    // col sums (mirrored tile coverage): lane (q,li) owns cols q*16+li and
    // 64+q*16+li; each of the 8 waves atomics its 16-row partial
    if (!diag) {
        float v0 = 0.f, v1 = 0.f;
        #pragma unroll
        for (int c = 0; c < 4; c++)
            if (q == c) { v0 = cs[c]; v1 = cs[c + 4]; }
        atomicAdd(&ns8[d * B_N + jc + q * 16 + li], v0);
        atomicAdd(&ns8[d * B_N + jc + 64 + q * 16 + li], v1);
    }
}

// ---------------------------------------------------------------------------
// Kernel 3: neg[b] = sum_d ns8[d][b] / (B-1); logits = pos/(pos+neg);
// loss = max + log(sum exp(l-max)) - mean(l). Shuffle-based reductions
// (verified R8).
// ---------------------------------------------------------------------------
__global__ void final_kernel(const float* __restrict__ pos,
                             const float* __restrict__ ns8,
                             float* __restrict__ out) {
    __shared__ float redm[4], reds[4], redl[4];
    int t = threadIdx.x, w = t >> 6, lane = t & 63;
    float vals[8];
    float lmax = -1e30f;
    #pragma unroll
    for (int i = 0; i < 8; i++) {
        int idx = t * 8 + i;
        float nsum = 0.f;
        #pragma unroll
        for (int d = 0; d < D_V; d++) nsum += ns8[d * B_N + idx];
        float p = pos[idx];
        float l = p / (p + nsum * (1.0f / (float)(B_N - 1)));
        vals[i] = l;
        lmax = fmaxf(lmax, l);
    }
    lmax = wave_reduce_max(lmax);
    if (lane == 0) redm[w] = lmax;
    __syncthreads();
    float m = fmaxf(fmaxf(redm[0], redm[1]), fmaxf(redm[2], redm[3]));
    float se = 0.f, sl = 0.f;
    #pragma unroll
    for (int i = 0; i < 8; i++) { se += expf(vals[i] - m); sl += vals[i]; }
    se = wave_reduce_sum(se);
    sl = wave_reduce_sum(sl);
    if (lane == 0) { reds[w] = se; redl[w] = sl; }
    __syncthreads();
    if (t == 0) {
        float S = reds[0] + reds[1] + reds[2] + reds[3];
        float L = redl[0] + redl[1] + redl[2] + redl[3];
        out[0] = m + logf(S) - L * (1.0f / (float)B_N);
    }
}

extern "C" void kernel_launch(void* const* d_in, const int* in_sizes, int n_in,
                              void* d_out, int out_size, void* d_ws, size_t ws_size,
                              hipStream_t stream) {
    const float* z = (const float*)d_in[0];
    float* out = (float*)d_out;
    unsigned short* zn = (unsigned short*)d_ws;                        // 8 MB bf16 (pre-scaled)
    float* ns8 = (float*)((char*)d_ws + (size_t)D_V * B_N * F_D * 2);  // 64 KB
    float* pos = ns8 + D_V * B_N;                                      // 8 KB

    np_kernel<<<dim3(512), 256, 0, stream>>>(z, zn, ns8, pos);
    neg_kernel<<<dim3(136 * 8), 512, 0, stream>>>(zn, ns8);
    final_kernel<<<1, 256, 0, stream>>>(pos, ns8, out);
}

// Round 10
// 86.601 us; speedup vs baseline: 1.1881x; 1.0023x over previous
//
#include <hip/hip_runtime.h>
#include <hip/hip_bf16.h>

#define B_N 2048
#define D_V 8
#define F_D 256
#define TILE 128
#define BC 32      // staging chunk: 32 B-cols per stage, double-buffered
#define LSTR 264   // 132 dwords == 4 (mod 32). For ds_*_b128, waves are serviced in
                   // 8-lane phases; lane li's 4-dword window starts at bank 4*li+c ->
                   // windows {0,4,...,28} tile all 32 banks: conflict-free.
                   // (557K at 264 = benign 2-way sub-phase aliasing, free per m136.
                   // 258 (==1): real 4-way, 1.67M, R2. 266 (==5): 2.79M, R5.)

// sqrt(2*log2(e)) : zn scaled by this => MFMA acc = 2*log2(e)*dot => exp(2*dot) = exp2(acc)
#define SCALE_F 1.69864364f

#if defined(__has_builtin)
#  if __has_builtin(__builtin_amdgcn_exp2f)
#    define EXP2F(x) __builtin_amdgcn_exp2f(x)
#  else
#    define EXP2F(x) exp2f(x)
#  endif
#else
#  define EXP2F(x) exp2f(x)
#endif

typedef __attribute__((ext_vector_type(8))) short short8;
typedef __attribute__((ext_vector_type(4))) float floatx4;

__device__ inline unsigned short f2bf(float f) {
    __hip_bfloat16 h = __float2bfloat16(f);
    return *reinterpret_cast<unsigned short*>(&h);
}

__device__ inline float wave_reduce_sum(float v) {
    #pragma unroll
    for (int off = 1; off < 64; off <<= 1)
        v += __shfl_xor(v, off, 64);
    return v;
}

__device__ inline float wave_reduce_max(float v) {
    #pragma unroll
    for (int off = 1; off < 64; off <<= 1)
        v = fmaxf(v, __shfl_xor(v, off, 64));
    return v;
}

// ---------------------------------------------------------------------------
// Kernel 1: fused normalize + pos (R1/R7-verified). Block = 256 threads
// (4 waves) handles 4 samples (32 rows). Each wave normalizes its sample's
// 8 rows (writes scaled bf16 zn to global [d][b][f] AND LDS), then waves 0/1
// compute pos for 2 samples each via MFMA from LDS. Zero-inits ns8.
// ---------------------------------------------------------------------------
__global__ __launch_bounds__(256)
void np_kernel(const float* __restrict__ z, unsigned short* __restrict__ zn,
               float* __restrict__ ns8, float* __restrict__ pos) {
    __shared__ __align__(16) unsigned short Zs[32 * LSTR];  // 16.5 KB
    int tid = threadIdx.x;
    int gid = blockIdx.x * 256 + tid;
    if (gid < D_V * B_N) ns8[gid] = 0.0f;

    int w = tid >> 6, lane = tid & 63;
    int b = blockIdx.x * 4 + w;  // this wave's sample
    #pragma unroll
    for (int k = 0; k < 8; k++) {
        const float4 v = ((const float4*)(z + ((size_t)b * 8 + k) * F_D))[lane];
        float ss = v.x * v.x + v.y * v.y + v.z * v.z + v.w * v.w;
        ss = wave_reduce_sum(ss);
        float inv = SCALE_F / fmaxf(sqrtf(ss), 1e-12f);
        ushort4 o;
        o.x = f2bf(v.x * inv);
        o.y = f2bf(v.y * inv);
        o.z = f2bf(v.z * inv);
        o.w = f2bf(v.w * inv);
        ((ushort4*)(zn + (size_t)k * (B_N * F_D) + (size_t)b * F_D))[lane] = o;
        *(ushort4*)(&Zs[(w * 8 + k) * LSTR + lane * 4]) = o;
    }
    __syncthreads();

    // pos: wave 0 -> local samples 0,1 ; wave 1 -> local samples 2,3
    if (w < 2) {
        int q = lane >> 4, li = lane & 15;
        int lr = (w * 2 + (li >> 3)) * 8 + (li & 7);  // local row: sample*8 + view
        short8 a[8];
        #pragma unroll
        for (int kk = 0; kk < 8; kk++)
            a[kk] = *(const short8*)(&Zs[lr * LSTR + kk * 32 + q * 8]);
        floatx4 acc = {0.f, 0.f, 0.f, 0.f};
        #pragma unroll
        for (int kk = 0; kk < 8; kk++)
            acc = __builtin_amdgcn_mfma_f32_16x16x32_bf16(a[kk], a[kk], acc, 0, 0, 0);
        float p0 = 0.f, p1 = 0.f;
        #pragma unroll
        for (int r = 0; r < 4; r++) {
            int row = q * 4 + r, col = li;
            bool same_sample = (row >> 3) == (col >> 3);
            if (same_sample && row != col) {
                float e = EXP2F(acc[r]);   // acc already = 2*log2e*dot
                if (row < 8) p0 += e; else p1 += e;
            }
        }
        p0 = wave_reduce_sum(p0);
        p1 = wave_reduce_sum(p1);
        if (lane == 0) {
            int s0 = blockIdx.x * 4 + w * 2;
            pos[s0] = p0;
            pos[s0 + 1] = p1;
        }
    }
}

// ---------------------------------------------------------------------------
// Kernel 2 (symmetric-halved): per view d, upper-triangle 128x128 tiles of
// S = exp(2 * Z Z^T): row-sums -> ns8[d][rows]; off-diag tiles also
// col-sums -> ns8[d][cols] (mirrored tile).
// Round-10: phase-diversity repartition. Each 128x128 tile is split into
// TWO 64-row blocks (half = upper/lower 64 A-rows); block = 256 thr
// (4 waves x 16 rows). B staged 32 cols/stage into double-buffered LDS
// (2 x 16.5 KB = 33 KB), R8's verified 1-barrier-per-stage schedule with
// T14 depth-2 prefetch (loads for stage s+2 issued after stage s+1 write).
// Live state a[8]=32 + breg[4]=32 + cs/rs/addr ~= 100 VGPR, NO launch-bounds
// squeeze (R8's forced cap spilled: WRITE 50.8 MB measured) -> 4 waves/SIMD
// = 4 resident blocks/CU (vs R9's 2), 4-wave barrier domains (vs 8),
// 8.5 blocks/CU in grid: stalls of one block covered by 3 others.
// Grid 2176 = 136 tiles x 2 halves x 8 views; both halves of a tile keep
// the same d = bid&7 -> same XCD (B-col L2 reuse preserved).
// ---------------------------------------------------------------------------
__global__ __launch_bounds__(256)
void neg_kernel(const unsigned short* __restrict__ zn,
                float* __restrict__ ns8) {
    __shared__ __align__(16) unsigned short Bs[2][BC * LSTR];  // 33 KB
    const int bid = blockIdx.x;
    const int d = bid & 7;            // view == XCD (perf heuristic; FETCH 10.4
                                      // vs 38.7 MB measured, R1 vs R2)
    int rest = bid >> 3;
    const int half = rest & 1;        // which 64-row half of the tile
    int trem = rest >> 1;             // 0..135 -> (i,j), i<=j
    int i = 0;
    while (trem >= 16 - i) { trem -= 16 - i; ++i; }
    const int j = i + trem;
    const bool diag = (i == j);
    const unsigned short* Z = zn + (size_t)d * (B_N * F_D);
    int tid = threadIdx.x, w = tid >> 6, lane = tid & 63;
    int q = lane >> 4, li = lane & 15;
    int r0 = i * TILE + half * 64 + w * 16;  // this wave's 16 A-rows
    const int jc = j * TILE;

    // A-frags: 32 VGPR resident whole kernel (16 rows, K=256)
    short8 a[8];
    #pragma unroll
    for (int kk = 0; kk < 8; kk++)
        a[kk] = *(const short8*)(Z + (size_t)(r0 + li) * F_D + kk * 32 + q * 8);

    // B staging: stage = 32 rows x 256 shorts = 1024 16B-chunks, 4 per thread
    short8 breg[4];
    #pragma unroll
    for (int it = 0; it < 4; ++it) {                    // loads for stage 0
        int idx = it * 256 + tid;
        int row = idx >> 5, kc = idx & 31;
        breg[it] = *(const short8*)(Z + (size_t)(jc + row) * F_D + kc * 8);
    }
    #pragma unroll
    for (int it = 0; it < 4; ++it) {                    // write stage 0 (vmcnt wait
        int idx = it * 256 + tid;                       //  = the one exposed latency)
        int row = idx >> 5, kc = idx & 31;
        *(short8*)(&Bs[0][row * LSTR + kc * 8]) = breg[it];
    }
    #pragma unroll
    for (int it = 0; it < 4; ++it) {                    // loads for stage 1 (T14)
        int idx = it * 256 + tid;
        int row = idx >> 5, kc = idx & 31;
        breg[it] = *(const short8*)(Z + (size_t)(jc + BC + row) * F_D + kc * 8);
    }

    float rs[4] = {0.f, 0.f, 0.f, 0.f};
    float cs[8];

    __syncthreads();

    #pragma unroll
    for (int st = 0; st < 4; ++st) {
        // ---- compute stage st from Bs[st&1] (32 cols = 2 ct-blocks) ----
        #pragma unroll
        for (int ct = 0; ct < 2; ++ct) {
            const unsigned short* bp = &Bs[st & 1][(ct * 16 + li) * LSTR + q * 8];
            floatx4 acc = {0.f, 0.f, 0.f, 0.f};
            #pragma unroll
            for (int kk = 0; kk < 8; kk++) {
                short8 bf = *(const short8*)(bp + kk * 32);
                acc = __builtin_amdgcn_mfma_f32_16x16x32_bf16(a[kk], bf, acc, 0, 0, 0);
            }
            // C/D layout: col = li, row(within 16-set) = q*4 + r
            const int g = st * 2 + ct;                 // 16-col group 0..7
            int gcol = jc + g * 16 + li;
            float csum = 0.f;
            #pragma unroll
            for (int r = 0; r < 4; r++) {
                float e = EXP2F(acc[r]);               // exp(2*dot), 1 trans op
                if (diag) {                            // uniform: 16/136 tiles
                    int grow = r0 + q * 4 + r;
                    if (grow == gcol) e = 0.f;
                }
                rs[r] += e;
                csum += e;
            }
            // col partial over this wave's 16 rows: reduce across q-groups
            csum += __shfl_xor(csum, 16, 64);
            csum += __shfl_xor(csum, 32, 64);
            cs[g] = csum;                              // static index
        }
        // ---- ds_write stage st+1 into the idle buffer (R8 schedule) ----
        if (st < 3) {
            #pragma unroll
            for (int it = 0; it < 4; ++it) {
                int idx = it * 256 + tid;
                int row = idx >> 5, kc = idx & 31;
                *(short8*)(&Bs[(st + 1) & 1][row * LSTR + kc * 8]) = breg[it];
            }
        }
        // ---- issue loads for stage st+2 (one compute stage covers latency) ----
        if (st < 2) {
            #pragma unroll
            for (int it = 0; it < 4; ++it) {
                int idx = it * 256 + tid;
                int row = idx >> 5, kc = idx & 31;
                breg[it] = *(const short8*)(Z + (size_t)(jc + (st + 2) * BC + row) * F_D + kc * 8);
            }
        }
        if (st < 3) __syncthreads();
    }

    // row sums: reduce across the 16 column-lanes; lanes li<4 own row q*4+li
    #pragma unroll
    for (int off = 1; off < 16; off <<= 1)
        #pragma unroll
        for (int r = 0; r < 4; r++)
            rs[r] += __shfl_xor(rs[r], off, 64);
    {
        float rv = 0.f;
        #pragma unroll
        for (int r = 0; r < 4; r++)
            if (li == r) rv = rs[r];
        if (li < 4)
            atomicAdd(&ns8[d * B_N + r0 + q * 4 + li], rv);
    }

    // col sums (mirrored tile coverage): lane (q,li) owns cols q*16+li and
    // 64+q*16+li; each of the 4 waves atomics its 16-row partial
    if (!diag) {
        float v0 = 0.f, v1 = 0.f;
        #pragma unroll
        for (int c = 0; c < 4; c++)
            if (q == c) { v0 = cs[c]; v1 = cs[c + 4]; }
        atomicAdd(&ns8[d * B_N + jc + q * 16 + li], v0);
        atomicAdd(&ns8[d * B_N + jc + 64 + q * 16 + li], v1);
    }
}

// ---------------------------------------------------------------------------
// Kernel 3: neg[b] = sum_d ns8[d][b] / (B-1); logits = pos/(pos+neg);
// loss = max + log(sum exp(l-max)) - mean(l). Shuffle-based reductions
// (verified R8/R9).
// ---------------------------------------------------------------------------
__global__ void final_kernel(const float* __restrict__ pos,
                             const float* __restrict__ ns8,
                             float* __restrict__ out) {
    __shared__ float redm[4], reds[4], redl[4];
    int t = threadIdx.x, w = t >> 6, lane = t & 63;
    float vals[8];
    float lmax = -1e30f;
    #pragma unroll
    for (int i = 0; i < 8; i++) {
        int idx = t * 8 + i;
        float nsum = 0.f;
        #pragma unroll
        for (int d = 0; d < D_V; d++) nsum += ns8[d * B_N + idx];
        float p = pos[idx];
        float l = p / (p + nsum * (1.0f / (float)(B_N - 1)));
        vals[i] = l;
        lmax = fmaxf(lmax, l);
    }
    lmax = wave_reduce_max(lmax);
    if (lane == 0) redm[w] = lmax;
    __syncthreads();
    float m = fmaxf(fmaxf(redm[0], redm[1]), fmaxf(redm[2], redm[3]));
    float se = 0.f, sl = 0.f;
    #pragma unroll
    for (int i = 0; i < 8; i++) { se += expf(vals[i] - m); sl += vals[i]; }
    se = wave_reduce_sum(se);
    sl = wave_reduce_sum(sl);
    if (lane == 0) { reds[w] = se; redl[w] = sl; }
    __syncthreads();
    if (t == 0) {
        float S = reds[0] + reds[1] + reds[2] + reds[3];
        float L = redl[0] + redl[1] + redl[2] + redl[3];
        out[0] = m + logf(S) - L * (1.0f / (float)B_N);
    }
}

extern "C" void kernel_launch(void* const* d_in, const int* in_sizes, int n_in,
                              void* d_out, int out_size, void* d_ws, size_t ws_size,
                              hipStream_t stream) {
    const float* z = (const float*)d_in[0];
    float* out = (float*)d_out;
    unsigned short* zn = (unsigned short*)d_ws;                        // 8 MB bf16 (pre-scaled)
    float* ns8 = (float*)((char*)d_ws + (size_t)D_V * B_N * F_D * 2);  // 64 KB
    float* pos = ns8 + D_V * B_N;                                      // 8 KB

    np_kernel<<<dim3(512), 256, 0, stream>>>(z, zn, ns8, pos);
    neg_kernel<<<dim3(136 * 2 * 8), 256, 0, stream>>>(zn, ns8);
    final_kernel<<<1, 256, 0, stream>>>(pos, ns8, out);
}